// Round 11
// baseline (55.725 us; speedup 1.0000x reference)
//
#include <hip/hip_runtime.h>
#include <hip/hip_bf16.h>

// Problem constants
#define NB 4
#define SEQ 2048
#define DM 1024
#define DH 64

typedef __attribute__((ext_vector_type(8))) short bf16x8;
typedef __attribute__((ext_vector_type(4))) float f32x4;
typedef __attribute__((ext_vector_type(4))) short short4v;

__device__ inline short f2bf(float f) {
  union { float f; unsigned u; } x; x.f = f;
  unsigned r = x.u + 0x7FFFu + ((x.u >> 16) & 1u);
  return (short)(r >> 16);
}

__device__ inline float bf2f(short s) {
  union { unsigned u; float f; } x;
  x.u = ((unsigned)(unsigned short)s) << 16;
  return x.f;
}

// ---------------------------------------------------------------------------
// Kernel 0: W fp32 -> bf16, once. wbf[192][1024]: rows 0-63 Wq, 64-127 Wk,
// 128-191 Wv.
// ---------------------------------------------------------------------------
__global__ __launch_bounds__(256) void wconv_kernel(
    const float* __restrict__ Wq, const float* __restrict__ Wk,
    const float* __restrict__ Wv, short* __restrict__ wbf)
{
  const int tid = blockIdx.x * 256 + threadIdx.x;
  const int base = tid * 8;
  const int row = base >> 10;          // 0..191
  const int col = base & 1023;
  const float* src = (row < 64) ? Wq : (row < 128) ? Wk : Wv;
  src += (size_t)(row & 63) * DM + col;
  f32x4 f0 = ((const f32x4*)src)[0];
  f32x4 f1 = ((const f32x4*)src)[1];
  bf16x8 h = { f2bf(f0[0]), f2bf(f0[1]), f2bf(f0[2]), f2bf(f0[3]),
               f2bf(f1[0]), f2bf(f1[1]), f2bf(f1[2]), f2bf(f1[3]) };
  *(bf16x8*)(wbf + (size_t)row * DM + col) = h;
}

// ---------------------------------------------------------------------------
// Kernel 1 (v3): QKV projection with W RESIDENT IN LDS (zero W re-staging).
// Grid (64, 4) x 512 threads = 1 block/CU. Block (bx, ks): W-quarter
// [192][256] bf16 loaded ONCE into LDS (96 KB, padded stride 264); block
// sweeps 4 M-tiles of 32 rows, staging only X (32 KB fp32/tile) with a
// single-reg-set prefetch across M-tiles (full compute-phase latency cover).
// Writes bf16 partials pacc[4][8192][192].
// ---------------------------------------------------------------------------
__global__ __launch_bounds__(512) void proj_v3_kernel(
    const float* __restrict__ X, const short* __restrict__ wbf,
    short* __restrict__ pacc)
{
  __shared__ short w_lds[192][264];     // 101,376 B
  __shared__ short x_lds[2][32][264];   //  33,792 B  (total 135 KB)

  const int t = threadIdx.x;
  const int l = t & 63;
  const int w = t >> 6;                 // 0..7
  const int ks = blockIdx.y;            // K-quarter
  const int kbase = ks * 256;
  const int mbase = blockIdx.x * 128;   // 4 M-tiles x 32 rows

  // ---- load W quarter once (coalesced, from L2-resident wbf) ----
#pragma unroll
  for (int i = 0; i < 12; i++) {
    const int idx = t + i * 512;        // 0..6143
    const int row = idx >> 5;           // 0..191
    const int cb = idx & 31;            // 16B chunk
    *(bf16x8*)&w_lds[row][cb * 8] =
        *(const bf16x8*)(wbf + (size_t)row * DM + kbase + cb * 8);
  }

  const int xr0 = t >> 6;               // 0..7
  const int xc0 = (t & 63) * 4;         // float col 0..252

  // prologue: load + store X tile 0
  f32x4 xp0, xp1, xp2, xp3;
  {
    const float* base = X + (size_t)(mbase + xr0) * DM + kbase + xc0;
    xp0 = *(const f32x4*)(base + 0 * 8 * DM);
    xp1 = *(const f32x4*)(base + 1 * 8 * DM);
    xp2 = *(const f32x4*)(base + 2 * 8 * DM);
    xp3 = *(const f32x4*)(base + 3 * 8 * DM);
  }
  {
    short4v h0 = { f2bf(xp0[0]), f2bf(xp0[1]), f2bf(xp0[2]), f2bf(xp0[3]) };
    short4v h1 = { f2bf(xp1[0]), f2bf(xp1[1]), f2bf(xp1[2]), f2bf(xp1[3]) };
    short4v h2 = { f2bf(xp2[0]), f2bf(xp2[1]), f2bf(xp2[2]), f2bf(xp2[3]) };
    short4v h3 = { f2bf(xp3[0]), f2bf(xp3[1]), f2bf(xp3[2]), f2bf(xp3[3]) };
    *(short4v*)&x_lds[0][xr0 + 0][xc0]  = h0;
    *(short4v*)&x_lds[0][xr0 + 8][xc0]  = h1;
    *(short4v*)&x_lds[0][xr0 + 16][xc0] = h2;
    *(short4v*)&x_lds[0][xr0 + 24][xc0] = h3;
  }
  __syncthreads();

  const int arow = (w & 1) * 16 + (l & 15);   // x_lds row
  const int kk = (l >> 4) << 3;               // frag k-offset
  const int cg = (w >> 1) * 3;                // first of 3 col-frags
  short* pp = pacc + (size_t)ks * (NB * SEQ) * 192;

#pragma unroll
  for (int mt = 0; mt < 4; mt++) {
    const int buf = mt & 1;

    // prefetch next M-tile's X (in flight during the whole compute phase)
    if (mt < 3) {
      const float* base = X + (size_t)(mbase + (mt + 1) * 32 + xr0) * DM + kbase + xc0;
      xp0 = *(const f32x4*)(base + 0 * 8 * DM);
      xp1 = *(const f32x4*)(base + 1 * 8 * DM);
      xp2 = *(const f32x4*)(base + 2 * 8 * DM);
      xp3 = *(const f32x4*)(base + 3 * 8 * DM);
    }

    // compute: 8 K-steps of 32, acc 1 M-frag x 3 N-frags
    f32x4 acc0 = (f32x4){0.f, 0.f, 0.f, 0.f};
    f32x4 acc1 = (f32x4){0.f, 0.f, 0.f, 0.f};
    f32x4 acc2 = (f32x4){0.f, 0.f, 0.f, 0.f};
#pragma unroll
    for (int k8 = 0; k8 < 8; k8++) {
      const int kc = k8 * 32 + kk;
      bf16x8 a  = *(const bf16x8*)&x_lds[buf][arow][kc];
      bf16x8 b0 = *(const bf16x8*)&w_lds[(cg + 0) * 16 + (l & 15)][kc];
      acc0 = __builtin_amdgcn_mfma_f32_16x16x32_bf16(a, b0, acc0, 0, 0, 0);
      bf16x8 b1 = *(const bf16x8*)&w_lds[(cg + 1) * 16 + (l & 15)][kc];
      acc1 = __builtin_amdgcn_mfma_f32_16x16x32_bf16(a, b1, acc1, 0, 0, 0);
      bf16x8 b2 = *(const bf16x8*)&w_lds[(cg + 2) * 16 + (l & 15)][kc];
      acc2 = __builtin_amdgcn_mfma_f32_16x16x32_bf16(a, b2, acc2, 0, 0, 0);
    }

    // epilogue: bf16 partial. C row=(lane>>4)*4+reg, col=cf*16+(lane&15) [m89]
    {
      const int rowb = mbase + mt * 32 + (w & 1) * 16 + ((l >> 4) << 2);
      const int c0 = (cg + 0) * 16 + (l & 15);
      const int c1 = (cg + 1) * 16 + (l & 15);
      const int c2 = (cg + 2) * 16 + (l & 15);
#pragma unroll
      for (int j = 0; j < 4; j++) {
        pp[(size_t)(rowb + j) * 192 + c0] = f2bf(acc0[j]);
        pp[(size_t)(rowb + j) * 192 + c1] = f2bf(acc1[j]);
        pp[(size_t)(rowb + j) * 192 + c2] = f2bf(acc2[j]);
      }
    }

    // write prefetched X into the other buffer
    if (mt < 3) {
      short4v h0 = { f2bf(xp0[0]), f2bf(xp0[1]), f2bf(xp0[2]), f2bf(xp0[3]) };
      short4v h1 = { f2bf(xp1[0]), f2bf(xp1[1]), f2bf(xp1[2]), f2bf(xp1[3]) };
      short4v h2 = { f2bf(xp2[0]), f2bf(xp2[1]), f2bf(xp2[2]), f2bf(xp2[3]) };
      short4v h3 = { f2bf(xp3[0]), f2bf(xp3[1]), f2bf(xp3[2]), f2bf(xp3[3]) };
      *(short4v*)&x_lds[buf ^ 1][xr0 + 0][xc0]  = h0;
      *(short4v*)&x_lds[buf ^ 1][xr0 + 8][xc0]  = h1;
      *(short4v*)&x_lds[buf ^ 1][xr0 + 16][xc0] = h2;
      *(short4v*)&x_lds[buf ^ 1][xr0 + 24][xc0] = h3;
    }
    __syncthreads();
  }
}

// ---------------------------------------------------------------------------
// Kernel 1b: reduce 4 K-split partials, route to q (x1/32), k, vt.
// ---------------------------------------------------------------------------
__global__ __launch_bounds__(256) void reduce4_kernel(
    const short* __restrict__ pacc, short* __restrict__ qout,
    short* __restrict__ kout, short* __restrict__ vtout)
{
  const int gid = blockIdx.x * 256 + threadIdx.x;   // 0 .. 8192*48-1
  const int r = gid / 48;
  const int cg = gid - r * 48;
  const int c0 = cg * 4;

  float v0 = 0.f, v1 = 0.f, v2 = 0.f, v3 = 0.f;
#pragma unroll
  for (int s = 0; s < 4; s++) {
    const short4v a = *(const short4v*)(pacc + ((size_t)s * (NB * SEQ) + r) * 192 + c0);
    v0 += bf2f(a[0]); v1 += bf2f(a[1]); v2 += bf2f(a[2]); v3 += bf2f(a[3]);
  }

  if (c0 < 64) {
    short4v h = { f2bf(v0 * 0.03125f), f2bf(v1 * 0.03125f),
                  f2bf(v2 * 0.03125f), f2bf(v3 * 0.03125f) };
    *(short4v*)(qout + (size_t)r * DH + c0) = h;
  } else if (c0 < 128) {
    short4v h = { f2bf(v0), f2bf(v1), f2bf(v2), f2bf(v3) };
    *(short4v*)(kout + (size_t)r * DH + (c0 - 64)) = h;
  } else {
    const int bb = r >> 11, s = r & (SEQ - 1);
    short* vt = vtout + (size_t)bb * DH * SEQ + (size_t)(c0 - 128) * SEQ + s;
    vt[0 * SEQ] = f2bf(v0);
    vt[1 * SEQ] = f2bf(v1);
    vt[2 * SEQ] = f2bf(v2);
    vt[3 * SEQ] = f2bf(v3);
  }
}

// ---------------------------------------------------------------------------
// Fallback proj (R9 verbatim, 48.5us-proven): used only if ws is too small
// for the pacc buffers. Writes qkv directly.
// ---------------------------------------------------------------------------
__global__ __launch_bounds__(512) void proj_fb_kernel(
    const float* __restrict__ X, const short* __restrict__ wbf,
    short* __restrict__ qout, short* __restrict__ kout,
    short* __restrict__ vtout)
{
  __shared__ short x_lds[2][32][80];
  __shared__ short w_lds[2][192][80];

  const int t = threadIdx.x;
  const int l = t & 63;
  const int w = t >> 6;
  const int m0 = blockIdx.x * 32;

  f32x4 acc[3];
#pragma unroll
  for (int i = 0; i < 3; i++) acc[i] = (f32x4){0.f, 0.f, 0.f, 0.f};

  const int xr = t >> 4;
  const int xc = (t & 15) * 4;
  const int wr = t >> 3;
  const int wc = (t & 7) * 8;

  const float* xsrc  = X   + (size_t)(m0 + xr) * DM + xc;
  const short* wsrc0 = wbf + (size_t)(wr)       * DM + wc;
  const short* wsrc1 = wbf + (size_t)(64 + wr)  * DM + wc;
  const short* wsrc2 = wbf + (size_t)(128 + wr) * DM + wc;

  {
    f32x4 f = *(const f32x4*)xsrc;
    short4v h = { f2bf(f[0]), f2bf(f[1]), f2bf(f[2]), f2bf(f[3]) };
    *(short4v*)&x_lds[0][xr][xc] = h;
    *(bf16x8*)&w_lds[0][wr][wc]       = *(const bf16x8*)wsrc0;
    *(bf16x8*)&w_lds[0][64 + wr][wc]  = *(const bf16x8*)wsrc1;
    *(bf16x8*)&w_lds[0][128 + wr][wc] = *(const bf16x8*)wsrc2;
  }
  f32x4 xA = *(const f32x4*)(xsrc + 64);
  bf16x8 wA0 = *(const bf16x8*)(wsrc0 + 64);
  bf16x8 wA1 = *(const bf16x8*)(wsrc1 + 64);
  bf16x8 wA2 = *(const bf16x8*)(wsrc2 + 64);
  f32x4 xB;
  bf16x8 wB0, wB1, wB2;
  __syncthreads();

#pragma unroll
  for (int it = 0; it < 16; it++) {
    const int buf = it & 1;
    const int k2 = (it + 2) * 64;

    if ((it & 1) == 0) {
      if (it + 2 < 16) {
        xB  = *(const f32x4*)(xsrc + k2);
        wB0 = *(const bf16x8*)(wsrc0 + k2);
        wB1 = *(const bf16x8*)(wsrc1 + k2);
        wB2 = *(const bf16x8*)(wsrc2 + k2);
      }
    } else {
      if (it + 2 < 16) {
        xA  = *(const f32x4*)(xsrc + k2);
        wA0 = *(const bf16x8*)(wsrc0 + k2);
        wA1 = *(const bf16x8*)(wsrc1 + k2);
        wA2 = *(const bf16x8*)(wsrc2 + k2);
      }
    }

    const short* xp = &x_lds[buf][(w & 1) * 16 + (l & 15)][(l >> 4) << 3];
    bf16x8 a0 = *(const bf16x8*)xp;
    bf16x8 a1 = *(const bf16x8*)(xp + 32);
#pragma unroll
    for (int nf = 0; nf < 3; nf++) {
      const int cf = (w >> 1) * 3 + nf;
      const short* wp = &w_lds[buf][cf * 16 + (l & 15)][(l >> 4) << 3];
      bf16x8 b0 = *(const bf16x8*)wp;
      bf16x8 b1 = *(const bf16x8*)(wp + 32);
      acc[nf] = __builtin_amdgcn_mfma_f32_16x16x32_bf16(a0, b0, acc[nf], 0, 0, 0);
      acc[nf] = __builtin_amdgcn_mfma_f32_16x16x32_bf16(a1, b1, acc[nf], 0, 0, 0);
    }

    if (it < 15) {
      if ((it & 1) == 0) {
        short4v h = { f2bf(xA[0]), f2bf(xA[1]), f2bf(xA[2]), f2bf(xA[3]) };
        *(short4v*)&x_lds[buf ^ 1][xr][xc] = h;
        *(bf16x8*)&w_lds[buf ^ 1][wr][wc]       = wA0;
        *(bf16x8*)&w_lds[buf ^ 1][64 + wr][wc]  = wA1;
        *(bf16x8*)&w_lds[buf ^ 1][128 + wr][wc] = wA2;
      } else {
        short4v h = { f2bf(xB[0]), f2bf(xB[1]), f2bf(xB[2]), f2bf(xB[3]) };
        *(short4v*)&x_lds[buf ^ 1][xr][xc] = h;
        *(bf16x8*)&w_lds[buf ^ 1][wr][wc]       = wB0;
        *(bf16x8*)&w_lds[buf ^ 1][64 + wr][wc]  = wB1;
        *(bf16x8*)&w_lds[buf ^ 1][128 + wr][wc] = wB2;
      }
    }
    __syncthreads();
  }

  const int rowb = m0 + (w & 1) * 16 + ((l >> 4) << 2);
#pragma unroll
  for (int nf = 0; nf < 3; nf++) {
    const int c = ((w >> 1) * 3 + nf) * 16 + (l & 15);
#pragma unroll
    for (int j = 0; j < 4; j++) {
      const int row = rowb + j;
      const float v = acc[nf][j];
      if (c < 64) {
        qout[row * DH + c] = f2bf(v * 0.03125f);
      } else if (c < 128) {
        kout[row * DH + (c - 64)] = f2bf(v);
      } else {
        const int b = row >> 11, s = row & (SEQ - 1);
        vtout[b * (DH * SEQ) + (c - 128) * SEQ + s] = f2bf(v);
      }
    }
  }
}

// ---------------------------------------------------------------------------
// Kernel 2: split-KV causal flash (unchanged).
// ---------------------------------------------------------------------------
__global__ __launch_bounds__(256) void flash_kernel(
    const short* __restrict__ qin, const short* __restrict__ kin,
    const short* __restrict__ vtin, float* __restrict__ po,
    float* __restrict__ pm, float* __restrict__ pl,
    const int nck, const int cht)
{
  __shared__ short k_lds[2][64][72];
  __shared__ short vt_lds[2][64][72];
  __shared__ short p_lds[4][16][72];

  const int qt = blockIdx.x;
  const int ck = blockIdx.y;
  const int t0 = ck * cht;
  if (t0 > qt) return;
  const int b = blockIdx.z;

  const int t = threadIdx.x;
  const int l = t & 63;
  const int w = t >> 6;
  const int q0 = qt * 64;
  const int tend = min(t0 + cht, qt + 1);

  const short* qb = qin  + (size_t)b * SEQ * DH;
  const short* kb = kin  + (size_t)b * SEQ * DH;
  const short* vb = vtin + (size_t)b * DH * SEQ;

  const short* qr = qb + (size_t)(q0 + w * 16 + (l & 15)) * DH + ((l >> 4) << 3);
  const bf16x8 qf0 = *(const bf16x8*)qr;
  const bf16x8 qf1 = *(const bf16x8*)(qr + 32);

  f32x4 o[4];
#pragma unroll
  for (int i = 0; i < 4; i++) o[i] = (f32x4){0.f, 0.f, 0.f, 0.f};
  float m_run[4] = {-1e30f, -1e30f, -1e30f, -1e30f};
  float l_run[4] = {0.f, 0.f, 0.f, 0.f};

  const int sr = t >> 3;
  const int sc = (t & 7) * 8;

  {
    const int j0 = t0 * 64;
#pragma unroll
    for (int i = 0; i < 2; i++) {
      const int r = sr + i * 32;
      *(bf16x8*)&k_lds[0][r][sc]  = *(const bf16x8*)(kb + (size_t)(j0 + r) * DH + sc);
      *(bf16x8*)&vt_lds[0][r][sc] = *(const bf16x8*)(vb + (size_t)r * SEQ + j0 + sc);
    }
  }
  __syncthreads();

  for (int tt = t0; tt < tend; tt++) {
    const int bi = (tt - t0) & 1;
    const int j0 = tt * 64;
    const bool pf = (tt + 1 < tend);

    bf16x8 kpf0, kpf1, vpf0, vpf1;
    if (pf) {
      const int j1 = j0 + 64;
      kpf0 = *(const bf16x8*)(kb + (size_t)(j1 + sr) * DH + sc);
      kpf1 = *(const bf16x8*)(kb + (size_t)(j1 + sr + 32) * DH + sc);
      vpf0 = *(const bf16x8*)(vb + (size_t)sr * SEQ + j1 + sc);
      vpf1 = *(const bf16x8*)(vb + (size_t)(sr + 32) * SEQ + j1 + sc);
    }

    f32x4 s[4];
#pragma unroll
    for (int nf = 0; nf < 4; nf++) {
      const short* kr = &k_lds[bi][nf * 16 + (l & 15)][(l >> 4) << 3];
      bf16x8 b0 = *(const bf16x8*)kr;
      bf16x8 b1 = *(const bf16x8*)(kr + 32);
      f32x4 a = (f32x4){0.f, 0.f, 0.f, 0.f};
      a = __builtin_amdgcn_mfma_f32_16x16x32_bf16(qf0, b0, a, 0, 0, 0);
      a = __builtin_amdgcn_mfma_f32_16x16x32_bf16(qf1, b1, a, 0, 0, 0);
      s[nf] = a;
    }

    {
      const int growb = q0 + w * 16 + ((l >> 4) << 2);
#pragma unroll
      for (int nf = 0; nf < 4; nf++) {
        const int gcol = j0 + nf * 16 + (l & 15);
#pragma unroll
        for (int j = 0; j < 4; j++)
          if (gcol > growb + j) s[nf][j] = -1e30f;
      }
    }

    float alpha[4];
#pragma unroll
    for (int j = 0; j < 4; j++) {
      float tm = fmaxf(fmaxf(s[0][j], s[1][j]), fmaxf(s[2][j], s[3][j]));
      tm = fmaxf(tm, __shfl_xor(tm, 1));
      tm = fmaxf(tm, __shfl_xor(tm, 2));
      tm = fmaxf(tm, __shfl_xor(tm, 4));
      tm = fmaxf(tm, __shfl_xor(tm, 8));
      const float mn = fmaxf(m_run[j], tm);
      alpha[j] = exp2f((m_run[j] - mn) * 1.44269504f);
      m_run[j] = mn;
      float rs = 0.f;
#pragma unroll
      for (int nf = 0; nf < 4; nf++) {
        const float p = exp2f((s[nf][j] - mn) * 1.44269504f);
        s[nf][j] = p;
        rs += p;
      }
      rs += __shfl_xor(rs, 1);
      rs += __shfl_xor(rs, 2);
      rs += __shfl_xor(rs, 4);
      rs += __shfl_xor(rs, 8);
      l_run[j] = l_run[j] * alpha[j] + rs;
    }
#pragma unroll
    for (int df = 0; df < 4; df++)
#pragma unroll
      for (int j = 0; j < 4; j++) o[df][j] *= alpha[j];

#pragma unroll
    for (int nf = 0; nf < 4; nf++)
#pragma unroll
      for (int j = 0; j < 4; j++)
        p_lds[w][((l >> 4) << 2) + j][nf * 16 + (l & 15)] = f2bf(s[nf][j]);

    asm volatile("s_waitcnt lgkmcnt(0)" ::: "memory");
    __builtin_amdgcn_sched_barrier(0);

#pragma unroll
    for (int ks = 0; ks < 2; ks++) {
      const short* pr = &p_lds[w][l & 15][ks * 32 + ((l >> 4) << 3)];
      const bf16x8 pa = *(const bf16x8*)pr;
#pragma unroll
      for (int df = 0; df < 4; df++) {
        const short* vr = &vt_lds[bi][df * 16 + (l & 15)][ks * 32 + ((l >> 4) << 3)];
        const bf16x8 vf = *(const bf16x8*)vr;
        o[df] = __builtin_amdgcn_mfma_f32_16x16x32_bf16(pa, vf, o[df], 0, 0, 0);
      }
    }

    if (pf) {
      *(bf16x8*)&k_lds[bi ^ 1][sr][sc]       = kpf0;
      *(bf16x8*)&k_lds[bi ^ 1][sr + 32][sc]  = kpf1;
      *(bf16x8*)&vt_lds[bi ^ 1][sr][sc]      = vpf0;
      *(bf16x8*)&vt_lds[bi ^ 1][sr + 32][sc] = vpf1;
    }
    __syncthreads();
  }

  const int rowb = q0 + w * 16 + ((l >> 4) << 2);
#pragma unroll
  for (int j = 0; j < 4; j++) {
    const size_t rowg = (size_t)b * SEQ + rowb + j;
#pragma unroll
    for (int df = 0; df < 4; df++)
      po[(rowg * nck + ck) * DH + df * 16 + (l & 15)] = o[df][j];
    if ((l & 15) == 0) {
      pm[rowg * nck + ck] = m_run[j];
      pl[rowg * nck + ck] = l_run[j];
    }
  }
}

// ---------------------------------------------------------------------------
// Kernel 3: merge partials (unchanged).
// ---------------------------------------------------------------------------
__global__ __launch_bounds__(256) void merge_kernel(
    const float* __restrict__ po, const float* __restrict__ pm,
    const float* __restrict__ pl, float* __restrict__ out,
    const int nck, const int ckshift)
{
  const int gid = blockIdx.x * 256 + threadIdx.x;
  const int r = gid >> 6;
  const int d = gid & 63;
  const int s = r & (SEQ - 1);
  const int C = (s >> ckshift) + 1;

  float m = -1e30f;
  for (int c = 0; c < C; c++) m = fmaxf(m, pm[r * nck + c]);
  float den = 0.f, num = 0.f;
  for (int c = 0; c < C; c++) {
    const float wgt = exp2f((pm[r * nck + c] - m) * 1.44269504f);
    den += pl[r * nck + c] * wgt;
    num += po[(size_t)(r * nck + c) * DH + d] * wgt;
  }
  out[gid] = num / den;
}

extern "C" void kernel_launch(void* const* d_in, const int* in_sizes, int n_in,
                              void* d_out, int out_size, void* d_ws, size_t ws_size,
                              hipStream_t stream) {
  const float* X  = (const float*)d_in[0];
  const float* Wq = (const float*)d_in[1];
  const float* Wk = (const float*)d_in[2];
  const float* Wv = (const float*)d_in[3];

  const size_t nrow = (size_t)NB * SEQ;              // 8192
  short* qws  = (short*)d_ws;                        // [8192][64] bf16
  short* kws  = qws + nrow * DH;
  short* vtws = kws + nrow * DH;
  const size_t qkv_bytes = 3 * nrow * DH * sizeof(short);   // 3.15 MB

  // Big layout: qkv | pacc [4][8192][192] bf16 (12.58MB) | wbf (0.39MB)
  //   - flash's po/pm/pl (8.65MB) alias the dead pacc region afterwards.
  // Need: 3.15 + 12.58 + 0.39 = 16.12 MB.
  const size_t big_need = qkv_bytes + 4 * nrow * 192 * sizeof(short)
                        + 192 * DM * sizeof(short);

  if (ws_size >= big_need) {
    short* pacc = vtws + nrow * DH;
    short* wbf  = pacc + 4 * nrow * 192;
    float* po   = (float*)pacc;
    float* pm   = po + nrow * 4 * DH;
    float* pl   = pm + nrow * 4;

    wconv_kernel<<<dim3(96), 256, 0, stream>>>(Wq, Wk, Wv, wbf);
    proj_v3_kernel<<<dim3(64, 4), 512, 0, stream>>>(X, wbf, pacc);
    reduce4_kernel<<<dim3((int)(nrow * 48 / 256)), 256, 0, stream>>>(pacc, qws, kws, vtws);
    flash_kernel<<<dim3(SEQ / 64, 4, NB), 256, 0, stream>>>(qws, kws, vtws, po, pm, pl, 4, 8);
    merge_kernel<<<dim3(NB * SEQ * DH / 256), 256, 0, stream>>>(po, pm, pl, (float*)d_out, 4, 9);
  } else {
    // R9-proven fallback layout: qkv | po/pm/pl (wbf aliases po start)
    float* po  = (float*)(vtws + nrow * DH);
    short* wbf = (short*)po;

    int nck, cht, ckshift;
    const size_t need4 = qkv_bytes + nrow * 4 * (DH + 2) * sizeof(float);
    if (ws_size >= need4) { nck = 4; cht = 8;  ckshift = 9;  }
    else                  { nck = 1; cht = 32; ckshift = 11; }
    float* pm = po + nrow * nck * DH;
    float* pl = pm + nrow * nck;

    wconv_kernel<<<dim3(96), 256, 0, stream>>>(Wq, Wk, Wv, wbf);
    proj_fb_kernel<<<dim3(NB * SEQ / 32), 512, 0, stream>>>(X, wbf, qws, kws, vtws);
    flash_kernel<<<dim3(SEQ / 64, nck, NB), 256, 0, stream>>>(qws, kws, vtws, po, pm, pl, nck, cht);
    merge_kernel<<<dim3(NB * SEQ * DH / 256), 256, 0, stream>>>(po, pm, pl, (float*)d_out, nck, ckshift);
  }
}